// Round 18
// baseline (92.442 us; speedup 1.0000x reference)
//
#include <hip/hip_runtime.h>
#include <hip/hip_bf16.h>
#include <stdint.h>

// Problem constants (CompressedKVAttention_11708080848911)
#define Bc    4
#define Hc    32
#define HKVc  8
#define QLc   16
#define KVc   8192
#define Dc    128
#define NREPc 4   // H / HKV
#define THR   8.0f   // defer-max threshold (T13); P <= 2^8, P''<=5243 < fp16 max

typedef _Float16 f16x8 __attribute__((ext_vector_type(8)));
typedef _Float16 f16x4 __attribute__((ext_vector_type(4)));
typedef float f32x4  __attribute__((ext_vector_type(4)));
typedef int   i32x4  __attribute__((ext_vector_type(4)));
typedef uint32_t u32x2 __attribute__((ext_vector_type(2)));

// Pack two sign-extended-int8 dwords into one half2 = (x0+1152, x1+1152).
// fp16 0x6400|u = 1024+u (u in [0,255] exact); u = byte^0x80 = x+128.
__device__ __forceinline__ uint32_t pk1152(int x0, int x1) {
  return (__builtin_amdgcn_perm((uint32_t)x1, (uint32_t)x0, 0x05040100u)
          & 0x00FF00FFu) ^ 0x64806480u;
}

// Raw barrier WITHOUT the vmcnt(0) drain __syncthreads carries (m97).
#define BAR() do {                                            \
    asm volatile("s_waitcnt lgkmcnt(0)" ::: "memory");        \
    __builtin_amdgcn_sched_barrier(0);                        \
    __builtin_amdgcn_s_barrier();                             \
  } while (0)

// ---------------------------------------------------------------------------
// R17: KVBLK=64 (merge two 32-token tiles into ONE compute phase).
// R15 (79us) ~= R16 (81us): barrier count and bank conflicts exonerated; the
// residual is the per-slot serial chain (ds_read -> QK chain -> 2 cross-lane
// shfl -> exp -> PV) exposed 8x per block at 4 waves/SIMD. This round halves
// the slot count at CONSTANT barrier rate (2 BARs / 64 tokens, same as R16):
//  - the two LDS buffers now hold the two HALVES of a 64-token tile;
//  - QK: 16 MFMAs as 4 independent depth-4 chains (2x ILP);
//  - softmax: ONE max-reduce + ONE defer-max vote per 64 tokens (the
//    ~100cy/op cross-lane chain halves per token);
//  - PV: 16 MFMAs, 8 independent acc chains of depth 2;
//  - prefetch: one super-tile deep = same 64 VGPR as R16's two sets.
// Tripwire: VGPR <= 128 (m69: >128 halves waves/SIMD); WRITE ~33 MB.
// Base: swapped QK^T, in-register P, prefolded LDS scales, T13 defer-max,
// T5 setprio, fp16 pk1152 dequant, K swizzle both sides, raw s_barrier.
// ---------------------------------------------------------------------------
__global__ __launch_bounds__(256) void attn_partial(
    const float* __restrict__ q, const int* __restrict__ kc,
    const int* __restrict__ vc,
    const float* __restrict__ ksc, const float* __restrict__ kzr,
    const float* __restrict__ vsc, const float* __restrict__ vzr,
    float* __restrict__ ws_acc, float* __restrict__ ws_m,
    float* __restrict__ ws_l, int nsplit)
{
  __shared__ __align__(16) unsigned short Klds[2][32][128]; // fp16, 16 KB
  __shared__ __align__(16) unsigned short Vlds[2][128][36]; // fp16, 18.4 KB
  __shared__ __align__(16) float          Sl[4][256];       // scales, 4 KB

  const int bid   = blockIdx.x;
  const int split = bid % nsplit;
  const int bg    = bid / nsplit;          // 0..31  (= b*HKV + g)
  const int chunk = KVc / nsplit;
  const int t_begin = split * chunk;
  const int nt2   = chunk >> 6;            // 64-token super-tiles

  const int tid  = threadIdx.x;
  const int wave = tid >> 6;
  const int lane = tid & 63;
  const int l15  = lane & 15;
  const int lg   = lane >> 4;              // 0..3

  const int b = bg >> 3, g = bg & 7;
  const int h = (g << 2) + wave;           // this wave's query head

  // ---- Q fragments (fp16) + per-row sum of fp16-rounded Q ----
  f16x8 qa[4];
  float qsum = 0.f;
  const float* qrow = q + ((size_t)((b * Hc + h) * QLc + l15)) * Dc;
#pragma unroll
  for (int ks = 0; ks < 4; ++ks) {
    const f32x4* qv = (const f32x4*)(qrow + ks * 32 + (lg << 3));
    f32x4 qlo = qv[0], qhi = qv[1];
    f16x8 f;
#pragma unroll
    for (int j = 0; j < 4; ++j) {
      f[j]     = (_Float16)qlo[j];
      f[4 + j] = (_Float16)qhi[j];
      qsum += (float)f[j] + (float)f[4 + j];   // post-rounding values
    }
    qa[ks] = f;
  }
  qsum += __shfl_xor(qsum, 16);
  qsum += __shfl_xor(qsum, 32);            // every lane: qsum of row (lane&15)

  const float QK_SCALE = 0.088388347648f * 1.44269504089f; // d^-1/2 * log2(e)

  float m = -1e30f, ell = 0.f, corr = 0.f;     // per-lane: row l15 stats
  f32x4 acc[8];
#pragma unroll
  for (int dt = 0; dt < 8; ++dt) acc[dt] = (f32x4){0.f, 0.f, 0.f, 0.f};

  const int*   kb   = kc  + (size_t)bg * KVc * Dc;
  const int*   vb   = vc  + (size_t)bg * KVc * Dc;
  const float* kscb = ksc + (size_t)bg * KVc;
  const float* kzrb = kzr + (size_t)bg * KVc;
  const float* vscb = vsc + (size_t)bg * KVc;
  const float* vzrb = vzr + (size_t)bg * KVc;

  // staging coords
  const int kt  = tid >> 3;                // K: token 0..31
  const int kd  = (tid & 7) << 4;          // K: d base (dwords in / halves out)
  const int ksw = (kt & 7) << 3;           // K col swizzle (u16-index XOR)
  const int tq  = tid >> 5;                // V: token group 0..7
  const int dq  = (tid & 31) << 2;         // V: d base 0,4,...,124
  const int tb  = (tq << 2) ^ ((((dq >> 4) & 3)) << 3);  // swizzled col base

  i32x4 kpA[4], vpA[4], kpB[4], vpB[4];    // prefetch: one 64-token pair

#define ISSUE(KP, VP, TILE) do {                                             \
    const int _t0 = t_begin + ((TILE) << 5);                                 \
    const int* _ks = kb + (size_t)(_t0 + kt) * Dc + kd;                      \
    KP[0] = ((const i32x4*)_ks)[0]; KP[1] = ((const i32x4*)_ks)[1];          \
    KP[2] = ((const i32x4*)_ks)[2]; KP[3] = ((const i32x4*)_ks)[3];          \
    VP[0] = *(const i32x4*)(vb + (size_t)(_t0 + (tq << 2) + 0) * Dc + dq);   \
    VP[1] = *(const i32x4*)(vb + (size_t)(_t0 + (tq << 2) + 1) * Dc + dq);   \
    VP[2] = *(const i32x4*)(vb + (size_t)(_t0 + (tq << 2) + 2) * Dc + dq);   \
    VP[3] = *(const i32x4*)(vb + (size_t)(_t0 + (tq << 2) + 3) * Dc + dq);   \
  } while (0)

#define WRITE(KP, VP, BUF) do {                                              \
    i32x4 _kA, _kB;                                                          \
    _kA[0]=(int)pk1152(KP[0][0],KP[0][1]); _kA[1]=(int)pk1152(KP[0][2],KP[0][3]); \
    _kA[2]=(int)pk1152(KP[1][0],KP[1][1]); _kA[3]=(int)pk1152(KP[1][2],KP[1][3]); \
    _kB[0]=(int)pk1152(KP[2][0],KP[2][1]); _kB[1]=(int)pk1152(KP[2][2],KP[2][3]); \
    _kB[2]=(int)pk1152(KP[3][0],KP[3][1]); _kB[3]=(int)pk1152(KP[3][2],KP[3][3]); \
    *(i32x4*)&Klds[BUF][kt][kd ^ ksw]       = _kA;                           \
    *(i32x4*)&Klds[BUF][kt][(kd + 8) ^ ksw] = _kB;                           \
    _Pragma("unroll")                                                        \
    for (int _j = 0; _j < 4; ++_j) {                                         \
      u32x2 _pk;                                                             \
      _pk[0] = pk1152(VP[0][_j], VP[1][_j]);                                 \
      _pk[1] = pk1152(VP[2][_j], VP[3][_j]);                                 \
      *(u32x2*)&Vlds[BUF][dq + _j][tb] = _pk;                                \
    }                                                                        \
  } while (0)

  // Prefolded scale restage for a 256-token window starting at WBASE.
#define RESTAGE(WBASE) do {                                                  \
    const int _arr = tid >> 6;                                               \
    const int _sl  = (tid & 63) << 2;                                        \
    int _toff = _sl;                                                         \
    if (_toff > chunk - 4) _toff = chunk - 4;                                \
    const float* _sp = (_arr == 0) ? kscb : (_arr == 1) ? kzrb               \
                     : (_arr == 2) ? vscb : vzrb;                            \
    f32x4 _sv = *(const f32x4*)(_sp + (WBASE) + _toff);                      \
    if (_arr == 0) { _sv[0]*=QK_SCALE; _sv[1]*=QK_SCALE;                     \
                     _sv[2]*=QK_SCALE; _sv[3]*=QK_SCALE; }                   \
    else if (_arr == 2) { _sv[0]*=1024.f; _sv[1]*=1024.f;                    \
                          _sv[2]*=1024.f; _sv[3]*=1024.f; }                  \
    else { _sv[0]+=1152.f; _sv[1]+=1152.f; _sv[2]+=1152.f; _sv[3]+=1152.f; } \
    *(f32x4*)&Sl[_arr][_sl] = _sv;                                           \
  } while (0)

  // ---- prologue: super-tile 0 -> bufs; super-tile 1 -> reg sets ----
  ISSUE(kpA, vpA, 0);
  ISSUE(kpB, vpB, 1);
  RESTAGE(t_begin);                        // overlaps tile0 load latency
  WRITE(kpA, vpA, 0);
  WRITE(kpB, vpB, 1);
  if (nt2 > 1) { ISSUE(kpA, vpA, 2); ISSUE(kpB, vpB, 3); }
  BAR();

  for (int st = 0; st < nt2; ++st) {
    if (st && !(st & 3)) {                 // new 256-token scale window
      RESTAGE(t_begin + ((st >> 2) << 8)); // (fallback nsplit<32 only)
      BAR();
    }

    // ---- scales from LDS (prefolded; broadcast reads) ----
    const int tw = (st & 3) << 6;
    const f32x4 ksc0 = *(const f32x4*)&Sl[0][tw + (lg << 2)];
    const f32x4 ksc1 = *(const f32x4*)&Sl[0][tw + 16 + (lg << 2)];
    const f32x4 ksc2 = *(const f32x4*)&Sl[0][tw + 32 + (lg << 2)];
    const f32x4 ksc3 = *(const f32x4*)&Sl[0][tw + 48 + (lg << 2)];
    const f32x4 kzr0 = *(const f32x4*)&Sl[1][tw + (lg << 2)];
    const f32x4 kzr1 = *(const f32x4*)&Sl[1][tw + 16 + (lg << 2)];
    const f32x4 kzr2 = *(const f32x4*)&Sl[1][tw + 32 + (lg << 2)];
    const f32x4 kzr3 = *(const f32x4*)&Sl[1][tw + 48 + (lg << 2)];

    // ---- QK swapped: 16 MFMAs, 4 independent depth-4 chains ----
    f32x4 sc0 = (f32x4){0.f,0.f,0.f,0.f}, sc1 = (f32x4){0.f,0.f,0.f,0.f};
    f32x4 sc2 = (f32x4){0.f,0.f,0.f,0.f}, sc3 = (f32x4){0.f,0.f,0.f,0.f};
    __builtin_amdgcn_s_setprio(1);
#pragma unroll
    for (int ks = 0; ks < 4; ++ks) {
      const int ko = (ks * 32 + (lg << 3)) ^ ((l15 & 7) << 3);
      f16x8 kf0 = *(const f16x8*)&Klds[0][l15][ko];
      sc0 = __builtin_amdgcn_mfma_f32_16x16x32_f16(kf0, qa[ks], sc0, 0, 0, 0);
      f16x8 kf1 = *(const f16x8*)&Klds[0][16 + l15][ko];
      sc1 = __builtin_amdgcn_mfma_f32_16x16x32_f16(kf1, qa[ks], sc1, 0, 0, 0);
      f16x8 kf2 = *(const f16x8*)&Klds[1][l15][ko];
      sc2 = __builtin_amdgcn_mfma_f32_16x16x32_f16(kf2, qa[ks], sc2, 0, 0, 0);
      f16x8 kf3 = *(const f16x8*)&Klds[1][16 + l15][ko];
      sc3 = __builtin_amdgcn_mfma_f32_16x16x32_f16(kf3, qa[ks], sc3, 0, 0, 0);
    }
    __builtin_amdgcn_s_setprio(0);

    // ---- scores for all 64 tokens (scales prefolded) ----
    float s0[4], s1[4], s2[4], s3[4];
#pragma unroll
    for (int j = 0; j < 4; ++j) {
      s0[j] = ksc0[j] * (sc0[j] - kzr0[j] * qsum);
      s1[j] = ksc1[j] * (sc1[j] - kzr1[j] * qsum);
      s2[j] = ksc2[j] * (sc2[j] - kzr2[j] * qsum);
      s3[j] = ksc3[j] * (sc3[j] - kzr3[j] * qsum);
    }

    // ---- ONE max-reduce + ONE defer-max vote per 64 tokens ----
    float tm = fmaxf(fmaxf(fmaxf(s0[0], s0[1]), fmaxf(s0[2], s0[3])),
                     fmaxf(fmaxf(s1[0], s1[1]), fmaxf(s1[2], s1[3])));
    tm = fmaxf(tm, fmaxf(fmaxf(fmaxf(s2[0], s2[1]), fmaxf(s2[2], s2[3])),
                         fmaxf(fmaxf(s3[0], s3[1]), fmaxf(s3[2], s3[3]))));
    tm = fmaxf(tm, __shfl_xor(tm, 16));
    tm = fmaxf(tm, __shfl_xor(tm, 32));
    if (__any(tm > m + THR)) {             // rare after early tiles
      float nm = fmaxf(m, tm);
      float cf = exp2f(m - nm);
      m = nm;
      ell *= cf; corr *= cf;
      float cfq[4];
#pragma unroll
      for (int j = 0; j < 4; ++j) cfq[j] = __shfl(cf, (lg << 2) + j);
#pragma unroll
      for (int dt = 0; dt < 8; ++dt)
#pragma unroll
        for (int j = 0; j < 4; ++j) acc[dt][j] *= cfq[j];
    }

    // ---- P in registers (P'' = p*vs*1024, prefolded); corr on ROUNDED P'' --
    const f32x4 vsc0 = *(const f32x4*)&Sl[2][tw + (lg << 2)];
    const f32x4 vsc1 = *(const f32x4*)&Sl[2][tw + 16 + (lg << 2)];
    const f32x4 vsc2 = *(const f32x4*)&Sl[2][tw + 32 + (lg << 2)];
    const f32x4 vsc3 = *(const f32x4*)&Sl[2][tw + 48 + (lg << 2)];
    const f32x4 vzr0 = *(const f32x4*)&Sl[3][tw + (lg << 2)];
    const f32x4 vzr1 = *(const f32x4*)&Sl[3][tw + 16 + (lg << 2)];
    const f32x4 vzr2 = *(const f32x4*)&Sl[3][tw + 32 + (lg << 2)];
    const f32x4 vzr3 = *(const f32x4*)&Sl[3][tw + 48 + (lg << 2)];
    f16x8 ppA, ppB;
#pragma unroll
    for (int j = 0; j < 4; ++j) {
      float p0 = exp2f(s0[j] - m);
      float p1 = exp2f(s1[j] - m);
      float p2 = exp2f(s2[j] - m);
      float p3 = exp2f(s3[j] - m);
      ell += (p0 + p1) + (p2 + p3);
      _Float16 c0 = (_Float16)(p0 * vsc0[j]);
      _Float16 c1 = (_Float16)(p1 * vsc1[j]);
      _Float16 c2 = (_Float16)(p2 * vsc2[j]);
      _Float16 c3 = (_Float16)(p3 * vsc3[j]);
      corr += ((float)c0 * vzr0[j] + (float)c1 * vzr1[j])
            + ((float)c2 * vzr2[j] + (float)c3 * vzr3[j]);
      ppA[j] = c0; ppA[4 + j] = c1;        // tokens 4lg+j / 16+4lg+j
      ppB[j] = c2; ppB[4 + j] = c3;        // tokens 32+4lg+j / 48+4lg+j
    }

    // ---- PV: 16 MFMAs, 8 independent acc chains of depth 2 ----
    __builtin_amdgcn_s_setprio(1);
#pragma unroll
    for (int dt = 0; dt < 8; ++dt) {
      const int swz = (dt & 3) << 3;
      f16x4 vA0 = *(const f16x4*)&Vlds[0][(dt << 4) + l15][(lg << 2) ^ swz];
      f16x4 vA1 = *(const f16x4*)&Vlds[0][(dt << 4) + l15][(16 + (lg << 2)) ^ swz];
      f16x8 vfA = __builtin_shufflevector(vA0, vA1, 0, 1, 2, 3, 4, 5, 6, 7);
      acc[dt] = __builtin_amdgcn_mfma_f32_16x16x32_f16(ppA, vfA, acc[dt], 0, 0, 0);
      f16x4 vB0 = *(const f16x4*)&Vlds[1][(dt << 4) + l15][(lg << 2) ^ swz];
      f16x4 vB1 = *(const f16x4*)&Vlds[1][(dt << 4) + l15][(16 + (lg << 2)) ^ swz];
      f16x8 vfB = __builtin_shufflevector(vB0, vB1, 0, 1, 2, 3, 4, 5, 6, 7);
      acc[dt] = __builtin_amdgcn_mfma_f32_16x16x32_f16(ppB, vfB, acc[dt], 0, 0, 0);
    }
    __builtin_amdgcn_s_setprio(0);

    // ---- locked section: stage super-tile st+1; issue st+2 ----
    if (st + 1 < nt2) {
      BAR();                               // readers done (no vmcnt drain)
      WRITE(kpA, vpA, 0);                  // counted vmcnt waits here
      WRITE(kpB, vpB, 1);
      if (st + 2 < nt2) {
        ISSUE(kpA, vpA, ((st + 2) << 1));
        ISSUE(kpB, vpB, ((st + 2) << 1) + 1);
      }
      BAR();                               // writes visible (lgkmcnt only)
    }
  }

  // ---- final reductions: ell/corr across lg groups (row l15) ----
  ell += __shfl_xor(ell, 16);  ell += __shfl_xor(ell, 32);
  corr += __shfl_xor(corr, 16); corr += __shfl_xor(corr, 32);
  float corrq[4];
#pragma unroll
  for (int j = 0; j < 4; ++j) corrq[j] = __shfl(corr, (lg << 2) + j);

  const size_t pbase = ((size_t)bg * nsplit + split) * 64;
  const float inv1k = 0.0009765625f;       // 1/1024 (undo P'' scaling)
#pragma unroll
  for (int dt = 0; dt < 8; ++dt)
#pragma unroll
    for (int j = 0; j < 4; ++j) {
      int row = (wave << 4) + (lg << 2) + j;   // q-row
      int d   = (dt << 4) + l15;
      ws_acc[(pbase + row) * Dc + d] = (acc[dt][j] - corrq[j]) * inv1k;
    }
  if (lg == 0) {
    ws_m[pbase + (wave << 4) + l15] = m;
    ws_l[pbase + (wave << 4) + l15] = ell;
  }
#undef ISSUE
#undef WRITE
#undef RESTAGE
}

// ---------------------------------------------------------------------------
// Phase 2: flash-combine partials and normalize. One block per (bg,row).
// ---------------------------------------------------------------------------
__global__ __launch_bounds__(128) void attn_combine(
    const float* __restrict__ ws_acc, const float* __restrict__ ws_m,
    const float* __restrict__ ws_l, float* __restrict__ out, int nsplit)
{
  const int r   = blockIdx.x;      // 0 .. 32*64-1
  const int bg  = r >> 6;
  const int row = r & 63;
  const int d   = threadIdx.x;     // 0..127

  float M = -1e30f;
#pragma unroll 4
  for (int i = 0; i < nsplit; ++i)
    M = fmaxf(M, ws_m[((size_t)bg * nsplit + i) * 64 + row]);
  float L = 0.f, o = 0.f;
#pragma unroll 4
  for (int i = 0; i < nsplit; ++i) {
    size_t pb = ((size_t)bg * nsplit + i) * 64 + row;
    float w = exp2f(ws_m[pb] - M);
    L += ws_l[pb] * w;
    o += ws_acc[pb * Dc + d] * w;
  }
  const int b = bg >> 3, g = bg & 7;
  const int rep = row >> 4, qq = row & 15;
  out[(((size_t)(b * Hc + g * NREPc + rep)) * QLc + qq) * Dc + d] = o / L;
}

extern "C" void kernel_launch(void* const* d_in, const int* in_sizes, int n_in,
                              void* d_out, int out_size, void* d_ws,
                              size_t ws_size, hipStream_t stream) {
  const float* q   = (const float*)d_in[0];
  const int*   kc  = (const int*)d_in[1];   // int8 values promoted to int32
  const int*   vc  = (const int*)d_in[2];
  const float* ksc = (const float*)d_in[3];
  const float* kzr = (const float*)d_in[4];
  const float* vsc = (const float*)d_in[5];
  const float* vzr = (const float*)d_in[6];
  float* out = (float*)d_out;

  int nsplit = 32;                         // 1024 blocks = 4/CU (residency
  while (nsplit > 1) {                     // cap) -> no sequential rounds
    size_t need = (size_t)32 * nsplit * 64 * (Dc + 2) * sizeof(float);
    if (need <= ws_size) break;
    nsplit >>= 1;
  }
  float* ws_acc = (float*)d_ws;                             // [32,ns,64,128]
  float* ws_m   = ws_acc + (size_t)32 * nsplit * 64 * Dc;   // [32,ns,64]
  float* ws_l   = ws_m   + (size_t)32 * nsplit * 64;        // [32,ns,64]

  attn_partial<<<dim3(32 * nsplit), dim3(256), 0, stream>>>(
      q, kc, vc, ksc, kzr, vsc, vzr, ws_acc, ws_m, ws_l, nsplit);
  attn_combine<<<dim3(32 * 64), dim3(128), 0, stream>>>(
      ws_acc, ws_m, ws_l, out, nsplit);
}

// Round 19
// 73.788 us; speedup vs baseline: 1.2528x; 1.2528x over previous
//
#include <hip/hip_runtime.h>
#include <hip/hip_bf16.h>
#include <stdint.h>

// Problem constants (CompressedKVAttention_11708080848911)
#define Bc    4
#define Hc    32
#define HKVc  8
#define QLc   16
#define KVc   8192
#define Dc    128
#define NREPc 4   // H / HKV
#define THR   8.0f   // defer-max threshold (T13); P <= 2^8, P''<=5243 < fp16 max

typedef _Float16 f16x8 __attribute__((ext_vector_type(8)));
typedef _Float16 f16x4 __attribute__((ext_vector_type(4)));
typedef float f32x4  __attribute__((ext_vector_type(4)));
typedef int   i32x4  __attribute__((ext_vector_type(4)));
typedef uint32_t u32x2 __attribute__((ext_vector_type(2)));

// Pack two sign-extended-int8 dwords into one half2 = (x0+1152, x1+1152).
// fp16 0x6400|u = 1024+u (u in [0,255] exact); u = byte^0x80 = x+128.
__device__ __forceinline__ uint32_t pk1152(int x0, int x1) {
  return (__builtin_amdgcn_perm((uint32_t)x1, (uint32_t)x0, 0x05040100u)
          & 0x00FF00FFu) ^ 0x64806480u;
}

// Raw barrier WITHOUT the vmcnt(0) drain __syncthreads carries (m97).
#define BAR() do {                                            \
    asm volatile("s_waitcnt lgkmcnt(0)" ::: "memory");        \
    __builtin_amdgcn_sched_barrier(0);                        \
    __builtin_amdgcn_s_barrier();                             \
  } while (0)

// ---------------------------------------------------------------------------
// R18 = R15 (79.1us, best) + fp16 ws_acc partials (halve ws traffic).
// R17 lesson: KVBLK=64 pushed VGPR to 132 (>128 cliff) -> occupancy halved,
// 92us. Reverted. R16 lesson: single-BAR dbuf = flat -> barrier count
// exonerated. The only remaining identifiable tax: 33.5MB fp32 ws_acc
// written by partial + read by combine. fp16 halves both (~5-8us). Numerics:
// fp16 rel err 2^-11 on partials propagates to ~5e-4 absolute in out;
// total absmax ~1.5-2e-3 < 4.02e-3 threshold (pre-committed revert if trips).
// Base: swapped QK^T (mfma(K,Q)), in-register P, prefolded LDS scales,
// 2-deep named prefetch, T13 defer-max, T5 setprio, fp16 pk1152 dequant,
// K swizzle col^((row&7)<<3) both sides, V [d][t]+XOR+40-pad, single-buffered
// K/V, raw s_barrier (loads ride across barriers), nsplit=32 (4 blocks/CU).
// ---------------------------------------------------------------------------
__global__ __launch_bounds__(256) void attn_partial(
    const float* __restrict__ q, const int* __restrict__ kc,
    const int* __restrict__ vc,
    const float* __restrict__ ksc, const float* __restrict__ kzr,
    const float* __restrict__ vsc, const float* __restrict__ vzr,
    _Float16* __restrict__ ws_acc, float* __restrict__ ws_m,
    float* __restrict__ ws_l, int nsplit)
{
  __shared__ __align__(16) unsigned short Klds[32][128];   // fp16 bits, 8 KB
  __shared__ __align__(16) unsigned short Vlds[128][40];   // fp16 bits, 10 KB
  __shared__ __align__(16) float          Sl[4][256];      // scales, 4 KB

  const int bid   = blockIdx.x;
  const int split = bid % nsplit;
  const int bg    = bid / nsplit;          // 0..31  (= b*HKV + g)
  const int chunk = KVc / nsplit;
  const int t_begin = split * chunk;
  const int nt    = chunk >> 5;            // 32-token tiles

  const int tid  = threadIdx.x;
  const int wave = tid >> 6;
  const int lane = tid & 63;
  const int l15  = lane & 15;
  const int lg   = lane >> 4;              // 0..3

  const int b = bg >> 3, g = bg & 7;
  const int h = (g << 2) + wave;           // this wave's query head

  // ---- Q fragments (fp16) + per-row sum of fp16-rounded Q ----
  f16x8 qa[4];
  float qsum = 0.f;
  const float* qrow = q + ((size_t)((b * Hc + h) * QLc + l15)) * Dc;
#pragma unroll
  for (int ks = 0; ks < 4; ++ks) {
    const f32x4* qv = (const f32x4*)(qrow + ks * 32 + (lg << 3));
    f32x4 qlo = qv[0], qhi = qv[1];
    f16x8 f;
#pragma unroll
    for (int j = 0; j < 4; ++j) {
      f[j]     = (_Float16)qlo[j];
      f[4 + j] = (_Float16)qhi[j];
      qsum += (float)f[j] + (float)f[4 + j];   // post-rounding values
    }
    qa[ks] = f;
  }
  qsum += __shfl_xor(qsum, 16);
  qsum += __shfl_xor(qsum, 32);            // every lane: qsum of row (lane&15)

  const float QK_SCALE = 0.088388347648f * 1.44269504089f; // d^-1/2 * log2(e)

  float m = -1e30f, ell = 0.f, corr = 0.f;     // per-lane: row l15 stats
  f32x4 acc[8];
#pragma unroll
  for (int dt = 0; dt < 8; ++dt) acc[dt] = (f32x4){0.f, 0.f, 0.f, 0.f};

  const int*   kb   = kc  + (size_t)bg * KVc * Dc;
  const int*   vb   = vc  + (size_t)bg * KVc * Dc;
  const float* kscb = ksc + (size_t)bg * KVc;
  const float* kzrb = kzr + (size_t)bg * KVc;
  const float* vscb = vsc + (size_t)bg * KVc;
  const float* vzrb = vzr + (size_t)bg * KVc;

  // staging coords
  const int kt  = tid >> 3;                // K: token 0..31
  const int kd  = (tid & 7) << 4;          // K: d base (dwords in / halves out)
  const int ksw = (kt & 7) << 3;           // K col swizzle (u16-index XOR)
  const int tq  = tid >> 5;                // V: token group 0..7
  const int dq  = (tid & 31) << 2;         // V: d base 0,4,...,124
  const int tb  = (tq << 2) ^ ((((dq >> 4) & 3)) << 3);  // swizzled col base

  i32x4 kpA[4], vpA[4], kpB[4], vpB[4];    // two named prefetch sets

#define ISSUE(KP, VP, TILE) do {                                             \
    const int _t0 = t_begin + ((TILE) << 5);                                 \
    const int* _ks = kb + (size_t)(_t0 + kt) * Dc + kd;                      \
    KP[0] = ((const i32x4*)_ks)[0]; KP[1] = ((const i32x4*)_ks)[1];          \
    KP[2] = ((const i32x4*)_ks)[2]; KP[3] = ((const i32x4*)_ks)[3];          \
    VP[0] = *(const i32x4*)(vb + (size_t)(_t0 + (tq << 2) + 0) * Dc + dq);   \
    VP[1] = *(const i32x4*)(vb + (size_t)(_t0 + (tq << 2) + 1) * Dc + dq);   \
    VP[2] = *(const i32x4*)(vb + (size_t)(_t0 + (tq << 2) + 2) * Dc + dq);   \
    VP[3] = *(const i32x4*)(vb + (size_t)(_t0 + (tq << 2) + 3) * Dc + dq);   \
  } while (0)

#define WRITE(KP, VP) do {                                                   \
    i32x4 _kA, _kB;                                                          \
    _kA[0]=(int)pk1152(KP[0][0],KP[0][1]); _kA[1]=(int)pk1152(KP[0][2],KP[0][3]); \
    _kA[2]=(int)pk1152(KP[1][0],KP[1][1]); _kA[3]=(int)pk1152(KP[1][2],KP[1][3]); \
    _kB[0]=(int)pk1152(KP[2][0],KP[2][1]); _kB[1]=(int)pk1152(KP[2][2],KP[2][3]); \
    _kB[2]=(int)pk1152(KP[3][0],KP[3][1]); _kB[3]=(int)pk1152(KP[3][2],KP[3][3]); \
    *(i32x4*)&Klds[kt][kd ^ ksw]       = _kA;                                \
    *(i32x4*)&Klds[kt][(kd + 8) ^ ksw] = _kB;                                \
    _Pragma("unroll")                                                        \
    for (int _j = 0; _j < 4; ++_j) {                                         \
      u32x2 _pk;                                                             \
      _pk[0] = pk1152(VP[0][_j], VP[1][_j]);                                 \
      _pk[1] = pk1152(VP[2][_j], VP[3][_j]);                                 \
      *(u32x2*)&Vlds[dq + _j][tb] = _pk;                                     \
    }                                                                        \
  } while (0)

  // Prefolded scale restage for a 256-token window starting at WBASE.
#define RESTAGE(WBASE) do {                                                  \
    const int _arr = tid >> 6;                                               \
    const int _sl  = (tid & 63) << 2;                                        \
    int _toff = _sl;                                                         \
    if (_toff > chunk - 4) _toff = chunk - 4;                                \
    const float* _sp = (_arr == 0) ? kscb : (_arr == 1) ? kzrb               \
                     : (_arr == 2) ? vscb : vzrb;                            \
    f32x4 _sv = *(const f32x4*)(_sp + (WBASE) + _toff);                      \
    if (_arr == 0) { _sv[0]*=QK_SCALE; _sv[1]*=QK_SCALE;                     \
                     _sv[2]*=QK_SCALE; _sv[3]*=QK_SCALE; }                   \
    else if (_arr == 2) { _sv[0]*=1024.f; _sv[1]*=1024.f;                    \
                          _sv[2]*=1024.f; _sv[3]*=1024.f; }                  \
    else { _sv[0]+=1152.f; _sv[1]+=1152.f; _sv[2]+=1152.f; _sv[3]+=1152.f; } \
    *(f32x4*)&Sl[_arr][_sl] = _sv;                                           \
  } while (0)

  // ---- prologue: tile0 staged; tile1->A, tile2->B in flight; scales ----
  ISSUE(kpA, vpA, 0);
  RESTAGE(t_begin);                        // overlaps tile0 load latency
  WRITE(kpA, vpA);                         // waits tile0 loads
  if (nt > 1) ISSUE(kpA, vpA, 1);
  if (nt > 2) ISSUE(kpB, vpB, 2);
  BAR();

  for (int it = 0; it < nt; ++it) {
    if (it && !(it & 7)) {                 // new 256-token scale window
      RESTAGE(t_begin + ((it >> 3) << 8));
      BAR();
    }

    // ---- scales from LDS (prefolded; broadcast reads, off VMEM path) ----
    const int tw = (it & 7) << 5;
    const f32x4 ksc0 = *(const f32x4*)&Sl[0][tw + (lg << 2)];
    const f32x4 ksc1 = *(const f32x4*)&Sl[0][tw + 16 + (lg << 2)];
    const f32x4 kzr0 = *(const f32x4*)&Sl[1][tw + (lg << 2)];
    const f32x4 kzr1 = *(const f32x4*)&Sl[1][tw + 16 + (lg << 2)];
    const f32x4 vsc0 = *(const f32x4*)&Sl[2][tw + (lg << 2)];
    const f32x4 vsc1 = *(const f32x4*)&Sl[2][tw + 16 + (lg << 2)];
    const f32x4 vzr0 = *(const f32x4*)&Sl[3][tw + (lg << 2)];
    const f32x4 vzr1 = *(const f32x4*)&Sl[3][tw + 16 + (lg << 2)];

    // ---- QK swapped, split accumulator chains; setprio around MFMA ----
    f32x4 sA0 = (f32x4){0.f,0.f,0.f,0.f}, sA1 = (f32x4){0.f,0.f,0.f,0.f};
    f32x4 sB0 = (f32x4){0.f,0.f,0.f,0.f}, sB1 = (f32x4){0.f,0.f,0.f,0.f};
    __builtin_amdgcn_s_setprio(1);
#pragma unroll
    for (int ks = 0; ks < 2; ++ks) {
      f16x8 kfA = *(const f16x8*)
          &Klds[l15][(ks * 32 + (lg << 3)) ^ ((l15 & 7) << 3)];
      sA0 = __builtin_amdgcn_mfma_f32_16x16x32_f16(kfA, qa[ks], sA0, 0, 0, 0);
      f16x8 kfB = *(const f16x8*)
          &Klds[16 + l15][(ks * 32 + (lg << 3)) ^ ((l15 & 7) << 3)];
      sB0 = __builtin_amdgcn_mfma_f32_16x16x32_f16(kfB, qa[ks], sB0, 0, 0, 0);
    }
#pragma unroll
    for (int ks = 2; ks < 4; ++ks) {
      f16x8 kfA = *(const f16x8*)
          &Klds[l15][(ks * 32 + (lg << 3)) ^ ((l15 & 7) << 3)];
      sA1 = __builtin_amdgcn_mfma_f32_16x16x32_f16(kfA, qa[ks], sA1, 0, 0, 0);
      f16x8 kfB = *(const f16x8*)
          &Klds[16 + l15][(ks * 32 + (lg << 3)) ^ ((l15 & 7) << 3)];
      sB1 = __builtin_amdgcn_mfma_f32_16x16x32_f16(kfB, qa[ks], sB1, 0, 0, 0);
    }
    __builtin_amdgcn_s_setprio(0);
    const f32x4 scA = sA0 + sA1;
    const f32x4 scB = sB0 + sB1;

    // ---- scores (scales prefolded) ----
    float s0[4], s1[4];
#pragma unroll
    for (int j = 0; j < 4; ++j) {
      s0[j] = ksc0[j] * (scA[j] - kzr0[j] * qsum);
      s1[j] = ksc1[j] * (scB[j] - kzr1[j] * qsum);
    }

    // ---- T13 defer-max: rescale only when tile max exceeds m+THR ----
    float tm = fmaxf(fmaxf(fmaxf(s0[0], s0[1]), fmaxf(s0[2], s0[3])),
                     fmaxf(fmaxf(s1[0], s1[1]), fmaxf(s1[2], s1[3])));
    tm = fmaxf(tm, __shfl_xor(tm, 16));
    tm = fmaxf(tm, __shfl_xor(tm, 32));
    if (__any(tm > m + THR)) {             // rare after early tiles
      float nm = fmaxf(m, tm);
      float cf = exp2f(m - nm);
      m = nm;
      ell *= cf; corr *= cf;
      float cfq[4];
#pragma unroll
      for (int j = 0; j < 4; ++j) cfq[j] = __shfl(cf, (lg << 2) + j);
#pragma unroll
      for (int dt = 0; dt < 8; ++dt)
#pragma unroll
        for (int j = 0; j < 4; ++j) acc[dt][j] *= cfq[j];
    }

    // ---- P in registers (P'' = p*vs*1024, prefolded); corr on ROUNDED P'' --
    f16x8 pp;
#pragma unroll
    for (int j = 0; j < 4; ++j) {
      float pA = exp2f(s0[j] - m);
      float pB = exp2f(s1[j] - m);
      ell += pA + pB;
      _Float16 ca = (_Float16)(pA * vsc0[j]);
      _Float16 cb = (_Float16)(pB * vsc1[j]);
      corr += (float)ca * vzr0[j] + (float)cb * vzr1[j];
      pp[j]     = ca;                      // k-slot j   -> token 4lg+j
      pp[4 + j] = cb;                      // k-slot 4+j -> token 16+4lg+j
    }

    // ---- PV: acc = mfma(P, V); setprio around MFMA cluster ----
    __builtin_amdgcn_s_setprio(1);
#pragma unroll
    for (int dt = 0; dt < 8; ++dt) {
      const int swz = (dt & 3) << 3;
      f16x4 vA = *(const f16x4*)&Vlds[(dt << 4) + l15][(lg << 2) ^ swz];
      f16x4 vB = *(const f16x4*)&Vlds[(dt << 4) + l15][(16 + (lg << 2)) ^ swz];
      f16x8 vf = __builtin_shufflevector(vA, vB, 0, 1, 2, 3, 4, 5, 6, 7);
      acc[dt] = __builtin_amdgcn_mfma_f32_16x16x32_f16(pp, vf, acc[dt], 0, 0, 0);
    }
    __builtin_amdgcn_s_setprio(0);

    // ---- locked: write tile it+1 (2 computes in flight); reissue its set --
    if (it + 1 < nt) {
      if (it & 1) {
        BAR();
        WRITE(kpB, vpB);
        if (it + 3 < nt) ISSUE(kpB, vpB, it + 3);
        BAR();
      } else {
        BAR();
        WRITE(kpA, vpA);
        if (it + 3 < nt) ISSUE(kpA, vpA, it + 3);
        BAR();
      }
    }
  }

  // ---- final reductions: ell/corr across lg groups (row l15) ----
  ell += __shfl_xor(ell, 16);  ell += __shfl_xor(ell, 32);
  corr += __shfl_xor(corr, 16); corr += __shfl_xor(corr, 32);
  float corrq[4];
#pragma unroll
  for (int j = 0; j < 4; ++j) corrq[j] = __shfl(corr, (lg << 2) + j);

  const size_t pbase = ((size_t)bg * nsplit + split) * 64;
  const float inv1k = 0.0009765625f;       // 1/1024 (undo P'' scaling)
#pragma unroll
  for (int dt = 0; dt < 8; ++dt)
#pragma unroll
    for (int j = 0; j < 4; ++j) {
      int row = (wave << 4) + (lg << 2) + j;   // q-row
      int d   = (dt << 4) + l15;
      ws_acc[(pbase + row) * Dc + d] =
          (_Float16)((acc[dt][j] - corrq[j]) * inv1k);
    }
  if (lg == 0) {
    ws_m[pbase + (wave << 4) + l15] = m;
    ws_l[pbase + (wave << 4) + l15] = ell;
  }
#undef ISSUE
#undef WRITE
#undef RESTAGE
}

// ---------------------------------------------------------------------------
// Phase 2: flash-combine fp16 partials and normalize. One block per (bg,row).
// ---------------------------------------------------------------------------
__global__ __launch_bounds__(128) void attn_combine(
    const _Float16* __restrict__ ws_acc, const float* __restrict__ ws_m,
    const float* __restrict__ ws_l, float* __restrict__ out, int nsplit)
{
  const int r   = blockIdx.x;      // 0 .. 32*64-1
  const int bg  = r >> 6;
  const int row = r & 63;
  const int d   = threadIdx.x;     // 0..127

  float M = -1e30f;
#pragma unroll 4
  for (int i = 0; i < nsplit; ++i)
    M = fmaxf(M, ws_m[((size_t)bg * nsplit + i) * 64 + row]);
  float L = 0.f, o = 0.f;
#pragma unroll 4
  for (int i = 0; i < nsplit; ++i) {
    size_t pb = ((size_t)bg * nsplit + i) * 64 + row;
    float w = exp2f(ws_m[pb] - M);
    L += ws_l[pb] * w;
    o += (float)ws_acc[pb * Dc + d] * w;
  }
  const int b = bg >> 3, g = bg & 7;
  const int rep = row >> 4, qq = row & 15;
  out[(((size_t)(b * Hc + g * NREPc + rep)) * QLc + qq) * Dc + d] = o / L;
}

extern "C" void kernel_launch(void* const* d_in, const int* in_sizes, int n_in,
                              void* d_out, int out_size, void* d_ws,
                              size_t ws_size, hipStream_t stream) {
  const float* q   = (const float*)d_in[0];
  const int*   kc  = (const int*)d_in[1];   // int8 values promoted to int32
  const int*   vc  = (const int*)d_in[2];
  const float* ksc = (const float*)d_in[3];
  const float* kzr = (const float*)d_in[4];
  const float* vsc = (const float*)d_in[5];
  const float* vzr = (const float*)d_in[6];
  float* out = (float*)d_out;

  int nsplit = 32;                         // 1024 blocks = 4/CU (residency
  while (nsplit > 1) {                     // cap) -> no sequential rounds
    size_t need = (size_t)32 * nsplit * 64 *
                  ((size_t)Dc * sizeof(_Float16) + 2 * sizeof(float));
    if (need <= ws_size) break;
    nsplit >>= 1;
  }
  _Float16* ws_acc = (_Float16*)d_ws;                       // [32,ns,64,128]
  float* ws_m = (float*)(ws_acc + (size_t)32 * nsplit * 64 * Dc); // [32,ns,64]
  float* ws_l = ws_m + (size_t)32 * nsplit * 64;                  // [32,ns,64]

  attn_partial<<<dim3(32 * nsplit), dim3(256), 0, stream>>>(
      q, kc, vc, ksc, kzr, vsc, vzr, ws_acc, ws_m, ws_l, nsplit);
  attn_combine<<<dim3(32 * 64), dim3(128), 0, stream>>>(
      ws_acc, ws_m, ws_l, out, nsplit);
}

// Round 20
// 72.829 us; speedup vs baseline: 1.2693x; 1.0132x over previous
//
#include <hip/hip_runtime.h>
#include <hip/hip_bf16.h>
#include <stdint.h>

// Problem constants (CompressedKVAttention_11708080848911)
#define Bc    4
#define Hc    32
#define HKVc  8
#define QLc   16
#define KVc   8192
#define Dc    128
#define NREPc 4   // H / HKV
#define THR   8.0f   // defer-max threshold (T13); P <= 2^8, P''<=5243 < fp16 max

typedef _Float16 f16x8 __attribute__((ext_vector_type(8)));
typedef _Float16 f16x4 __attribute__((ext_vector_type(4)));
typedef float f32x4  __attribute__((ext_vector_type(4)));
typedef int   i32x4  __attribute__((ext_vector_type(4)));
typedef uint32_t u32x2 __attribute__((ext_vector_type(2)));

// Pack two sign-extended-int8 dwords into one half2 = (x0+1152, x1+1152).
// fp16 0x6400|u = 1024+u (u in [0,255] exact); u = byte^0x80 = x+128.
__device__ __forceinline__ uint32_t pk1152(int x0, int x1) {
  return (__builtin_amdgcn_perm((uint32_t)x1, (uint32_t)x0, 0x05040100u)
          & 0x00FF00FFu) ^ 0x64806480u;
}

// Raw barrier WITHOUT the vmcnt(0) drain __syncthreads carries (m97).
#define BAR() do {                                            \
    asm volatile("s_waitcnt lgkmcnt(0)" ::: "memory");        \
    __builtin_amdgcn_sched_barrier(0);                        \
    __builtin_amdgcn_s_barrier();                             \
  } while (0)

// ---------------------------------------------------------------------------
// R19 = R18 (73.8us) + defer-max FAST PATH: the 2 cross-lane shfl_xor
// (permlane-class, ~100+cy each, serial) that computed the wave-wide max
// every tile are moved INSIDE the rescale branch. The vote now uses the
// per-lane 8-token max (7 in-lane fmax only). Numerics identical: m updates
// only via the fully-reduced max (stays uniform per q-row); P stays bounded
// by 2^THR. Common path per tile loses ~200-400cy of serial cross-lane work.
// Ledger: R14 scale-prefold+defer-max -8us; R15 co-residency+setprio -21;
// R18 fp16 ws -5; barriers(R16)/granularity(R17,VGPR cliff)/independence
// (R10/R11)/staging mechanics(R6-R9) all measured-null or negative.
// Base: swapped QK^T (mfma(K,Q)), in-register P, prefolded LDS scales,
// 2-deep named prefetch, T5 setprio, fp16 pk1152 dequant, K swizzle
// col^((row&7)<<3) both sides, V [d][t]+XOR+40-pad, single-buffered K/V,
// raw s_barrier (loads ride across barriers), nsplit=32, fp16 ws partials.
// ---------------------------------------------------------------------------
__global__ __launch_bounds__(256) void attn_partial(
    const float* __restrict__ q, const int* __restrict__ kc,
    const int* __restrict__ vc,
    const float* __restrict__ ksc, const float* __restrict__ kzr,
    const float* __restrict__ vsc, const float* __restrict__ vzr,
    _Float16* __restrict__ ws_acc, float* __restrict__ ws_m,
    float* __restrict__ ws_l, int nsplit)
{
  __shared__ __align__(16) unsigned short Klds[32][128];   // fp16 bits, 8 KB
  __shared__ __align__(16) unsigned short Vlds[128][40];   // fp16 bits, 10 KB
  __shared__ __align__(16) float          Sl[4][256];      // scales, 4 KB

  const int bid   = blockIdx.x;
  const int split = bid % nsplit;
  const int bg    = bid / nsplit;          // 0..31  (= b*HKV + g)
  const int chunk = KVc / nsplit;
  const int t_begin = split * chunk;
  const int nt    = chunk >> 5;            // 32-token tiles

  const int tid  = threadIdx.x;
  const int wave = tid >> 6;
  const int lane = tid & 63;
  const int l15  = lane & 15;
  const int lg   = lane >> 4;              // 0..3

  const int b = bg >> 3, g = bg & 7;
  const int h = (g << 2) + wave;           // this wave's query head

  // ---- Q fragments (fp16) + per-row sum of fp16-rounded Q ----
  f16x8 qa[4];
  float qsum = 0.f;
  const float* qrow = q + ((size_t)((b * Hc + h) * QLc + l15)) * Dc;
#pragma unroll
  for (int ks = 0; ks < 4; ++ks) {
    const f32x4* qv = (const f32x4*)(qrow + ks * 32 + (lg << 3));
    f32x4 qlo = qv[0], qhi = qv[1];
    f16x8 f;
#pragma unroll
    for (int j = 0; j < 4; ++j) {
      f[j]     = (_Float16)qlo[j];
      f[4 + j] = (_Float16)qhi[j];
      qsum += (float)f[j] + (float)f[4 + j];   // post-rounding values
    }
    qa[ks] = f;
  }
  qsum += __shfl_xor(qsum, 16);
  qsum += __shfl_xor(qsum, 32);            // every lane: qsum of row (lane&15)

  const float QK_SCALE = 0.088388347648f * 1.44269504089f; // d^-1/2 * log2(e)

  float m = -1e30f, ell = 0.f, corr = 0.f;     // per-lane: row l15 stats
  f32x4 acc[8];
#pragma unroll
  for (int dt = 0; dt < 8; ++dt) acc[dt] = (f32x4){0.f, 0.f, 0.f, 0.f};

  const int*   kb   = kc  + (size_t)bg * KVc * Dc;
  const int*   vb   = vc  + (size_t)bg * KVc * Dc;
  const float* kscb = ksc + (size_t)bg * KVc;
  const float* kzrb = kzr + (size_t)bg * KVc;
  const float* vscb = vsc + (size_t)bg * KVc;
  const float* vzrb = vzr + (size_t)bg * KVc;

  // staging coords
  const int kt  = tid >> 3;                // K: token 0..31
  const int kd  = (tid & 7) << 4;          // K: d base (dwords in / halves out)
  const int ksw = (kt & 7) << 3;           // K col swizzle (u16-index XOR)
  const int tq  = tid >> 5;                // V: token group 0..7
  const int dq  = (tid & 31) << 2;         // V: d base 0,4,...,124
  const int tb  = (tq << 2) ^ ((((dq >> 4) & 3)) << 3);  // swizzled col base

  i32x4 kpA[4], vpA[4], kpB[4], vpB[4];    // two named prefetch sets

#define ISSUE(KP, VP, TILE) do {                                             \
    const int _t0 = t_begin + ((TILE) << 5);                                 \
    const int* _ks = kb + (size_t)(_t0 + kt) * Dc + kd;                      \
    KP[0] = ((const i32x4*)_ks)[0]; KP[1] = ((const i32x4*)_ks)[1];          \
    KP[2] = ((const i32x4*)_ks)[2]; KP[3] = ((const i32x4*)_ks)[3];          \
    VP[0] = *(const i32x4*)(vb + (size_t)(_t0 + (tq << 2) + 0) * Dc + dq);   \
    VP[1] = *(const i32x4*)(vb + (size_t)(_t0 + (tq << 2) + 1) * Dc + dq);   \
    VP[2] = *(const i32x4*)(vb + (size_t)(_t0 + (tq << 2) + 2) * Dc + dq);   \
    VP[3] = *(const i32x4*)(vb + (size_t)(_t0 + (tq << 2) + 3) * Dc + dq);   \
  } while (0)

#define WRITE(KP, VP) do {                                                   \
    i32x4 _kA, _kB;                                                          \
    _kA[0]=(int)pk1152(KP[0][0],KP[0][1]); _kA[1]=(int)pk1152(KP[0][2],KP[0][3]); \
    _kA[2]=(int)pk1152(KP[1][0],KP[1][1]); _kA[3]=(int)pk1152(KP[1][2],KP[1][3]); \
    _kB[0]=(int)pk1152(KP[2][0],KP[2][1]); _kB[1]=(int)pk1152(KP[2][2],KP[2][3]); \
    _kB[2]=(int)pk1152(KP[3][0],KP[3][1]); _kB[3]=(int)pk1152(KP[3][2],KP[3][3]); \
    *(i32x4*)&Klds[kt][kd ^ ksw]       = _kA;                                \
    *(i32x4*)&Klds[kt][(kd + 8) ^ ksw] = _kB;                                \
    _Pragma("unroll")                                                        \
    for (int _j = 0; _j < 4; ++_j) {                                         \
      u32x2 _pk;                                                             \
      _pk[0] = pk1152(VP[0][_j], VP[1][_j]);                                 \
      _pk[1] = pk1152(VP[2][_j], VP[3][_j]);                                 \
      *(u32x2*)&Vlds[dq + _j][tb] = _pk;                                     \
    }                                                                        \
  } while (0)

  // Prefolded scale restage for a 256-token window starting at WBASE.
#define RESTAGE(WBASE) do {                                                  \
    const int _arr = tid >> 6;                                               \
    const int _sl  = (tid & 63) << 2;                                        \
    int _toff = _sl;                                                         \
    if (_toff > chunk - 4) _toff = chunk - 4;                                \
    const float* _sp = (_arr == 0) ? kscb : (_arr == 1) ? kzrb               \
                     : (_arr == 2) ? vscb : vzrb;                            \
    f32x4 _sv = *(const f32x4*)(_sp + (WBASE) + _toff);                      \
    if (_arr == 0) { _sv[0]*=QK_SCALE; _sv[1]*=QK_SCALE;                     \
                     _sv[2]*=QK_SCALE; _sv[3]*=QK_SCALE; }                   \
    else if (_arr == 2) { _sv[0]*=1024.f; _sv[1]*=1024.f;                    \
                          _sv[2]*=1024.f; _sv[3]*=1024.f; }                  \
    else { _sv[0]+=1152.f; _sv[1]+=1152.f; _sv[2]+=1152.f; _sv[3]+=1152.f; } \
    *(f32x4*)&Sl[_arr][_sl] = _sv;                                           \
  } while (0)

  // ---- prologue: tile0 staged; tile1->A, tile2->B in flight; scales ----
  ISSUE(kpA, vpA, 0);
  RESTAGE(t_begin);                        // overlaps tile0 load latency
  WRITE(kpA, vpA);                         // waits tile0 loads
  if (nt > 1) ISSUE(kpA, vpA, 1);
  if (nt > 2) ISSUE(kpB, vpB, 2);
  BAR();

  for (int it = 0; it < nt; ++it) {
    if (it && !(it & 7)) {                 // new 256-token scale window
      RESTAGE(t_begin + ((it >> 3) << 8));
      BAR();
    }

    // ---- scales from LDS (prefolded; broadcast reads, off VMEM path) ----
    const int tw = (it & 7) << 5;
    const f32x4 ksc0 = *(const f32x4*)&Sl[0][tw + (lg << 2)];
    const f32x4 ksc1 = *(const f32x4*)&Sl[0][tw + 16 + (lg << 2)];
    const f32x4 kzr0 = *(const f32x4*)&Sl[1][tw + (lg << 2)];
    const f32x4 kzr1 = *(const f32x4*)&Sl[1][tw + 16 + (lg << 2)];
    const f32x4 vsc0 = *(const f32x4*)&Sl[2][tw + (lg << 2)];
    const f32x4 vsc1 = *(const f32x4*)&Sl[2][tw + 16 + (lg << 2)];
    const f32x4 vzr0 = *(const f32x4*)&Sl[3][tw + (lg << 2)];
    const f32x4 vzr1 = *(const f32x4*)&Sl[3][tw + 16 + (lg << 2)];

    // ---- QK swapped, split accumulator chains; setprio around MFMA ----
    f32x4 sA0 = (f32x4){0.f,0.f,0.f,0.f}, sA1 = (f32x4){0.f,0.f,0.f,0.f};
    f32x4 sB0 = (f32x4){0.f,0.f,0.f,0.f}, sB1 = (f32x4){0.f,0.f,0.f,0.f};
    __builtin_amdgcn_s_setprio(1);
#pragma unroll
    for (int ks = 0; ks < 2; ++ks) {
      f16x8 kfA = *(const f16x8*)
          &Klds[l15][(ks * 32 + (lg << 3)) ^ ((l15 & 7) << 3)];
      sA0 = __builtin_amdgcn_mfma_f32_16x16x32_f16(kfA, qa[ks], sA0, 0, 0, 0);
      f16x8 kfB = *(const f16x8*)
          &Klds[16 + l15][(ks * 32 + (lg << 3)) ^ ((l15 & 7) << 3)];
      sB0 = __builtin_amdgcn_mfma_f32_16x16x32_f16(kfB, qa[ks], sB0, 0, 0, 0);
    }
#pragma unroll
    for (int ks = 2; ks < 4; ++ks) {
      f16x8 kfA = *(const f16x8*)
          &Klds[l15][(ks * 32 + (lg << 3)) ^ ((l15 & 7) << 3)];
      sA1 = __builtin_amdgcn_mfma_f32_16x16x32_f16(kfA, qa[ks], sA1, 0, 0, 0);
      f16x8 kfB = *(const f16x8*)
          &Klds[16 + l15][(ks * 32 + (lg << 3)) ^ ((l15 & 7) << 3)];
      sB1 = __builtin_amdgcn_mfma_f32_16x16x32_f16(kfB, qa[ks], sB1, 0, 0, 0);
    }
    __builtin_amdgcn_s_setprio(0);
    const f32x4 scA = sA0 + sA1;
    const f32x4 scB = sB0 + sB1;

    // ---- scores (scales prefolded) ----
    float s0[4], s1[4];
#pragma unroll
    for (int j = 0; j < 4; ++j) {
      s0[j] = ksc0[j] * (scA[j] - kzr0[j] * qsum);
      s1[j] = ksc1[j] * (scB[j] - kzr1[j] * qsum);
    }

    // ---- defer-max fast path: vote on IN-LANE max only; cross-lane
    //      reduction + rescale only when some lane exceeds m+THR ----
    float tml = fmaxf(fmaxf(fmaxf(s0[0], s0[1]), fmaxf(s0[2], s0[3])),
                      fmaxf(fmaxf(s1[0], s1[1]), fmaxf(s1[2], s1[3])));
    if (__any(tml > m + THR)) {            // rare after early tiles
      float tm = fmaxf(tml, __shfl_xor(tml, 16));
      tm = fmaxf(tm, __shfl_xor(tm, 32));  // wave-reduced: uniform per q-row
      float nm = fmaxf(m, tm);
      float cf = exp2f(m - nm);
      m = nm;
      ell *= cf; corr *= cf;
      float cfq[4];
#pragma unroll
      for (int j = 0; j < 4; ++j) cfq[j] = __shfl(cf, (lg << 2) + j);
#pragma unroll
      for (int dt = 0; dt < 8; ++dt)
#pragma unroll
        for (int j = 0; j < 4; ++j) acc[dt][j] *= cfq[j];
    }

    // ---- P in registers (P'' = p*vs*1024, prefolded); corr on ROUNDED P'' --
    f16x8 pp;
#pragma unroll
    for (int j = 0; j < 4; ++j) {
      float pA = exp2f(s0[j] - m);
      float pB = exp2f(s1[j] - m);
      ell += pA + pB;
      _Float16 ca = (_Float16)(pA * vsc0[j]);
      _Float16 cb = (_Float16)(pB * vsc1[j]);
      corr += (float)ca * vzr0[j] + (float)cb * vzr1[j];
      pp[j]     = ca;                      // k-slot j   -> token 4lg+j
      pp[4 + j] = cb;                      // k-slot 4+j -> token 16+4lg+j
    }

    // ---- PV: acc = mfma(P, V); setprio around MFMA cluster ----
    __builtin_amdgcn_s_setprio(1);
#pragma unroll
    for (int dt = 0; dt < 8; ++dt) {
      const int swz = (dt & 3) << 3;
      f16x4 vA = *(const f16x4*)&Vlds[(dt << 4) + l15][(lg << 2) ^ swz];
      f16x4 vB = *(const f16x4*)&Vlds[(dt << 4) + l15][(16 + (lg << 2)) ^ swz];
      f16x8 vf = __builtin_shufflevector(vA, vB, 0, 1, 2, 3, 4, 5, 6, 7);
      acc[dt] = __builtin_amdgcn_mfma_f32_16x16x32_f16(pp, vf, acc[dt], 0, 0, 0);
    }
    __builtin_amdgcn_s_setprio(0);

    // ---- locked: write tile it+1 (2 computes in flight); reissue its set --
    if (it + 1 < nt) {
      if (it & 1) {
        BAR();
        WRITE(kpB, vpB);
        if (it + 3 < nt) ISSUE(kpB, vpB, it + 3);
        BAR();
      } else {
        BAR();
        WRITE(kpA, vpA);
        if (it + 3 < nt) ISSUE(kpA, vpA, it + 3);
        BAR();
      }
    }
  }

  // ---- final reductions: ell/corr across lg groups (row l15) ----
  ell += __shfl_xor(ell, 16);  ell += __shfl_xor(ell, 32);
  corr += __shfl_xor(corr, 16); corr += __shfl_xor(corr, 32);
  float corrq[4];
#pragma unroll
  for (int j = 0; j < 4; ++j) corrq[j] = __shfl(corr, (lg << 2) + j);

  const size_t pbase = ((size_t)bg * nsplit + split) * 64;
  const float inv1k = 0.0009765625f;       // 1/1024 (undo P'' scaling)
#pragma unroll
  for (int dt = 0; dt < 8; ++dt)
#pragma unroll
    for (int j = 0; j < 4; ++j) {
      int row = (wave << 4) + (lg << 2) + j;   // q-row
      int d   = (dt << 4) + l15;
      ws_acc[(pbase + row) * Dc + d] =
          (_Float16)((acc[dt][j] - corrq[j]) * inv1k);
    }
  if (lg == 0) {
    ws_m[pbase + (wave << 4) + l15] = m;
    ws_l[pbase + (wave << 4) + l15] = ell;
  }
#undef ISSUE
#undef WRITE
#undef RESTAGE
}

// ---------------------------------------------------------------------------
// Phase 2: flash-combine fp16 partials and normalize. One block per (bg,row).
// ---------------------------------------------------------------------------
__global__ __launch_bounds__(128) void attn_combine(
    const _Float16* __restrict__ ws_acc, const float* __restrict__ ws_m,
    const float* __restrict__ ws_l, float* __restrict__ out, int nsplit)
{
  const int r   = blockIdx.x;      // 0 .. 32*64-1
  const int bg  = r >> 6;
  const int row = r & 63;
  const int d   = threadIdx.x;     // 0..127

  float M = -1e30f;
#pragma unroll 4
  for (int i = 0; i < nsplit; ++i)
    M = fmaxf(M, ws_m[((size_t)bg * nsplit + i) * 64 + row]);
  float L = 0.f, o = 0.f;
#pragma unroll 4
  for (int i = 0; i < nsplit; ++i) {
    size_t pb = ((size_t)bg * nsplit + i) * 64 + row;
    float w = exp2f(ws_m[pb] - M);
    L += ws_l[pb] * w;
    o += (float)ws_acc[pb * Dc + d] * w;
  }
  const int b = bg >> 3, g = bg & 7;
  const int rep = row >> 4, qq = row & 15;
  out[(((size_t)(b * Hc + g * NREPc + rep)) * QLc + qq) * Dc + d] = o / L;
}

extern "C" void kernel_launch(void* const* d_in, const int* in_sizes, int n_in,
                              void* d_out, int out_size, void* d_ws,
                              size_t ws_size, hipStream_t stream) {
  const float* q   = (const float*)d_in[0];
  const int*   kc  = (const int*)d_in[1];   // int8 values promoted to int32
  const int*   vc  = (const int*)d_in[2];
  const float* ksc = (const float*)d_in[3];
  const float* kzr = (const float*)d_in[4];
  const float* vsc = (const float*)d_in[5];
  const float* vzr = (const float*)d_in[6];
  float* out = (float*)d_out;

  int nsplit = 32;                         // 1024 blocks = 4/CU (residency
  while (nsplit > 1) {                     // cap) -> no sequential rounds
    size_t need = (size_t)32 * nsplit * 64 *
                  ((size_t)Dc * sizeof(_Float16) + 2 * sizeof(float));
    if (need <= ws_size) break;
    nsplit >>= 1;
  }
  _Float16* ws_acc = (_Float16*)d_ws;                       // [32,ns,64,128]
  float* ws_m = (float*)(ws_acc + (size_t)32 * nsplit * 64 * Dc); // [32,ns,64]
  float* ws_l = ws_m + (size_t)32 * nsplit * 64;                  // [32,ns,64]

  attn_partial<<<dim3(32 * nsplit), dim3(256), 0, stream>>>(
      q, kc, vc, ksc, kzr, vsc, vzr, ws_acc, ws_m, ws_l, nsplit);
  attn_combine<<<dim3(32 * 64), dim3(128), 0, stream>>>(
      ws_acc, ws_m, ws_l, out, nsplit);
}